// Round 1
// baseline (332.533 us; speedup 1.0000x reference)
//
#include <hip/hip_runtime.h>
#include <math.h>

// Problem constants (reference: I=32, C=16, O=16, P=2, BATCH=1024)
#define BATCH   1024
#define ISIZE   32
#define CSIZE   16
#define OSIZE   16
// input row (i) stride = I*C = 512 floats; j stride = C = 16 floats
// per-batch input  = C*I*I = 16384 floats
// per-batch output = C*O*O = 4096 floats

__global__ __launch_bounds__(256) void pool3d_sqsum_sqrt(
    const float* __restrict__ x, float* __restrict__ out)
{
    const int tid = blockIdx.x * blockDim.x + threadIdx.x; // [0, BATCH*4096/4)

    // tid = b*1024 + oi*64 + oj*4 + c4  →  out offset = tid*4 (coalesced)
    const int c4 = tid & 3;
    const int oj = (tid >> 2) & 15;
    const int oi = (tid >> 6) & 15;
    const int b  = tid >> 10;

    const float* base = x + (size_t)b * (ISIZE * ISIZE * CSIZE)
                          + (oi << 1) * (ISIZE * CSIZE)   // i = 2*oi
                          + oj * (2 * CSIZE)              // j = 2*oj → 32*oj floats
                          + (c4 << 2);                    // 4 channels per thread

    // rows i=2oi and i=2oi+1; cols j=2oj and j=2oj+1 (16 floats apart)
    const float4 a0 = *(const float4*)(base);
    const float4 a1 = *(const float4*)(base + CSIZE);
    const float4 a2 = *(const float4*)(base + ISIZE * CSIZE);
    const float4 a3 = *(const float4*)(base + ISIZE * CSIZE + CSIZE);

    float4 y;
    y.x = sqrtf(a0.x * a0.x + a1.x * a1.x + a2.x * a2.x + a3.x * a3.x);
    y.y = sqrtf(a0.y * a0.y + a1.y * a1.y + a2.y * a2.y + a3.y * a3.y);
    y.z = sqrtf(a0.z * a0.z + a1.z * a1.z + a2.z * a2.z + a3.z * a3.z);
    y.w = sqrtf(a0.w * a0.w + a1.w * a1.w + a2.w * a2.w + a3.w * a3.w);

    *(float4*)(out + (size_t)tid * 4) = y;
}

extern "C" void kernel_launch(void* const* d_in, const int* in_sizes, int n_in,
                              void* d_out, int out_size, void* d_ws, size_t ws_size,
                              hipStream_t stream)
{
    const float* x = (const float*)d_in[0];   // [1024, 16384] fp32
    // d_in[1] is T — structurally constant 2x2 pooling matrix; not needed.
    float* out = (float*)d_out;               // [1024, 4096] fp32

    const int total_vec4 = BATCH * OSIZE * OSIZE * CSIZE / 4; // 1,048,576
    const int block = 256;
    const int grid  = total_vec4 / block;                     // 4096
    pool3d_sqsum_sqrt<<<grid, block, 0, stream>>>(x, out);
}

// Round 2
// 332.295 us; speedup vs baseline: 1.0007x; 1.0007x over previous
//
#include <hip/hip_runtime.h>
#include <math.h>

// Problem constants (reference: I=32, C=16, O=16, P=2, BATCH=1024)
#define BATCH   1024
#define ISIZE   32
#define CSIZE   16
#define OSIZE   16
// input layout [i][j][c]: c stride 1, j stride 16, i stride 512 floats
// per-batch input  = 16384 floats (64 KiB); per-batch output = 4096 floats (16 KiB)

// Each thread produces 8 contiguous output floats (one (oi,oj) site, half the
// channels): 8x float4 loads (4 window positions x 2 float4), 2x float4 stores.
// 524288 threads total; out offset = tid*8 -> fully coalesced stores.
__global__ __launch_bounds__(256) void pool3d_sqsum_sqrt(
    const float* __restrict__ x, float* __restrict__ out)
{
    const int tid = blockIdx.x * blockDim.x + threadIdx.x; // [0, 524288)

    // tid = b*512 + oi*32 + oj*2 + c8
    const int c8 = tid & 1;          // channel half: c = 8*c8 .. 8*c8+7
    const int oj = (tid >> 1) & 15;
    const int oi = (tid >> 5) & 15;
    const int b  = tid >> 9;

    const float* base = x + (size_t)b * (ISIZE * ISIZE * CSIZE)
                          + (oi << 1) * (ISIZE * CSIZE)   // i = 2*oi
                          + (oj << 1) * CSIZE             // j = 2*oj
                          + (c8 << 3);                    // 8 channels

    // 4 window positions: (r,jj) in {0,1}x{0,1}; each is 2 adjacent float4s
    const float4 p00a = *(const float4*)(base);
    const float4 p00b = *(const float4*)(base + 4);
    const float4 p01a = *(const float4*)(base + CSIZE);
    const float4 p01b = *(const float4*)(base + CSIZE + 4);
    const float4 p10a = *(const float4*)(base + ISIZE * CSIZE);
    const float4 p10b = *(const float4*)(base + ISIZE * CSIZE + 4);
    const float4 p11a = *(const float4*)(base + ISIZE * CSIZE + CSIZE);
    const float4 p11b = *(const float4*)(base + ISIZE * CSIZE + CSIZE + 4);

    float4 ya, yb;
    ya.x = sqrtf(p00a.x*p00a.x + p01a.x*p01a.x + p10a.x*p10a.x + p11a.x*p11a.x);
    ya.y = sqrtf(p00a.y*p00a.y + p01a.y*p01a.y + p10a.y*p10a.y + p11a.y*p11a.y);
    ya.z = sqrtf(p00a.z*p00a.z + p01a.z*p01a.z + p10a.z*p10a.z + p11a.z*p11a.z);
    ya.w = sqrtf(p00a.w*p00a.w + p01a.w*p01a.w + p10a.w*p10a.w + p11a.w*p11a.w);
    yb.x = sqrtf(p00b.x*p00b.x + p01b.x*p01b.x + p10b.x*p10b.x + p11b.x*p11b.x);
    yb.y = sqrtf(p00b.y*p00b.y + p01b.y*p01b.y + p10b.y*p10b.y + p11b.y*p11b.y);
    yb.z = sqrtf(p00b.z*p00b.z + p01b.z*p01b.z + p10b.z*p10b.z + p11b.z*p11b.z);
    yb.w = sqrtf(p00b.w*p00b.w + p01b.w*p01b.w + p10b.w*p10b.w + p11b.w*p11b.w);

    float* o = out + (size_t)tid * 8;
    *(float4*)(o)     = ya;
    *(float4*)(o + 4) = yb;
}

extern "C" void kernel_launch(void* const* d_in, const int* in_sizes, int n_in,
                              void* d_out, int out_size, void* d_ws, size_t ws_size,
                              hipStream_t stream)
{
    const float* x = (const float*)d_in[0];   // [1024, 16384] fp32
    // d_in[1] is T — structurally constant 2x2 pooling matrix; not needed.
    float* out = (float*)d_out;               // [1024, 4096] fp32

    const int total = BATCH * OSIZE * OSIZE * CSIZE / 8; // 524288 threads
    const int block = 256;
    const int grid  = total / block;                     // 2048
    pool3d_sqsum_sqrt<<<grid, block, 0, stream>>>(x, out);
}